// Round 14
// baseline (111.148 us; speedup 1.0000x reference)
//
#include <hip/hip_runtime.h>
#include <math.h>

#define INFBITS 0x7F800000u
#define TCH 128          // chamfer LDS tile (R9/R13-best)
#define PTS 8            // query points per thread
#define DICE_BLOCKS 512
#define SCAN_PER_DIR 32  // 8192/256
#define SCAN_BLOCKS (2 * SCAN_PER_DIR)

typedef float v2f __attribute__((ext_vector_type(2)));

// ---------- block-wide sum (blockDim.x == 256, 4 waves) ----------
__device__ __forceinline__ float block_sum256(float v) {
#pragma unroll
    for (int o = 32; o > 0; o >>= 1) v += __shfl_down(v, o, 64);
    __shared__ float sb[4];
    if ((threadIdx.x & 63) == 0) sb[threadIdx.x >> 6] = v;
    __syncthreads();
    float r = sb[0] + sb[1] + sb[2] + sb[3];
    __syncthreads();
    return r;
}

// ---------- single persistent kernel ----------
// blocks [0, 512)    : dice partials -> arrive cnt_dice
// blocks [512, 1024) : chamfer partials -> pm -> arrive cnt_cham;
//                      the first 64 then become SCANNERS: spin until
//                      cnt_cham==512, cross-chunk min + ||a||^2 + block-sum
//                      -> bsum -> arrive cnt_scan; last scanner polls
//                      cnt_dice==512 and combines everything into out.
// Co-residency: 1024 blocks at <=128 VGPR (launch_bounds 256,4), 1.5 KB LDS
// -> 4 blocks/CU vs capacity 8 -> all blocks resident -> spins can't deadlock.
__global__ void __launch_bounds__(256, 4) fused_one(
        const float4* __restrict__ p4, const float4* __restrict__ t4, int n4,
        float* __restrict__ inter_p, float* __restrict__ uni_p,
        const float2* __restrict__ P, const float2* __restrict__ T,
        int N, int M, float* __restrict__ pm, int npm, int chm, int gxp,
        int cham_blocks, int nch0, int nch1,
        float* __restrict__ bsum,
        unsigned int* __restrict__ cnt_dice,
        unsigned int* __restrict__ cnt_cham,
        unsigned int* __restrict__ cnt_scan,
        float* __restrict__ out) {
    int bid = blockIdx.x;
    int t   = threadIdx.x;

    if (bid < DICE_BLOCKS) {
        // ---- dice partial sums ----
        float inter = 0.f, uni = 0.f;
#pragma unroll 2
        for (int i = bid * 256 + t; i < n4; i += DICE_BLOCKS * 256) {
            float4 p = p4[i];
            float4 tt = t4[i];
            float s;
            s = __fdividef(1.f, 1.f + __expf(-p.x)); inter = fmaf(s, tt.x, inter); uni += s + tt.x;
            s = __fdividef(1.f, 1.f + __expf(-p.y)); inter = fmaf(s, tt.y, inter); uni += s + tt.y;
            s = __fdividef(1.f, 1.f + __expf(-p.z)); inter = fmaf(s, tt.z, inter); uni += s + tt.z;
            s = __fdividef(1.f, 1.f + __expf(-p.w)); inter = fmaf(s, tt.w, inter); uni += s + tt.w;
        }
        float bi = block_sum256(inter);
        float bu = block_sum256(uni);
        if (t == 0) { inter_p[bid] = bi; uni_p[bid] = bu; }
        __threadfence();
        __syncthreads();
        if (t == 0) atomicAdd(cnt_dice, 1u);
        return;
    }

    // ---- chamfer partials (R13 packed inner loop, byte-identical) ----
    int cb      = bid - DICE_BLOCKS;
    int per_dir = gxp * chm;
    int dir     = cb / per_dir;
    int rem     = cb - dir * per_dir;
    int cy      = rem / gxp;          // target chunk
    int cx      = rem - cy * gxp;     // query-point group
    {
        const float2* A = dir ? T : P;
        const float2* B = dir ? P : T;
        int nA = dir ? M : N;
        int nB = dir ? N : M;

        int tb = cy * TCH;
        if (tb < nB) {
            __shared__ __align__(16) float4 qs[TCH / 2];
            if (t < TCH / 2) {
                int j0 = tb + 2 * t;
                float4 r = make_float4(1e18f, 1e18f, 1e18f, 1e18f);  // pad never wins
                if (j0 + 1 < nB) {
                    float4 b = *(const float4*)&B[j0];               // {b0x,b0y,b1x,b1y}
                    r = make_float4(b.x, b.z, b.y, b.w);             // SoA pair swizzle
                } else if (j0 < nB) {
                    float2 b = B[j0];
                    r = make_float4(b.x, 1e18f, b.y, 1e18f);
                }
                qs[t] = r;
            }
            __syncthreads();

            int abase = cx * (PTS * 256);
            v2f nx2[PTS], ny2[PTS];
            float mn[PTS];
#pragma unroll
            for (int i = 0; i < PTS; ++i) {
                int p = abase + i * 256 + t;
                float nx = 0.f, ny = 0.f;
                mn[i] = __uint_as_float(INFBITS);
                if (p < nA) {
                    float2 a = A[p];
                    nx = -2.f * a.x;
                    ny = -2.f * a.y;
                }
                nx2[i] = (v2f){nx, nx};
                ny2[i] = (v2f){ny, ny};
            }

#pragma unroll 4
            for (int jp = 0; jp < TCH / 2; ++jp) {
                float4 q = qs[jp];                 // {b0x,b1x,b0y,b1y}
                v2f X = (v2f){q.x, q.y};
                v2f Y = (v2f){q.z, q.w};
                v2f S = X * X + Y * Y;
#pragma unroll
                for (int i = 0; i < PTS; ++i) {
                    v2f D = nx2[i] * X + (ny2[i] * Y + S);
                    mn[i] = fminf(fminf(mn[i], D.x), D.y);
                }
            }

            float* dstc = pm + ((size_t)dir * chm + cy) * npm;
#pragma unroll
            for (int i = 0; i < PTS; ++i) {
                int p = abase + i * 256 + t;
                if (p < nA) dstc[p] = mn[i];
            }
        }
    }
    // release pm, arrive
    __threadfence();
    __syncthreads();
    if (t == 0) atomicAdd(cnt_cham, 1u);

    if (cb >= SCAN_BLOCKS) return;

    // ---- scanner role (first 64 chamfer blocks) ----
    if (t == 0) {
        while (atomicAdd(cnt_cham, 0u) < (unsigned)cham_blocks)
            __builtin_amdgcn_s_sleep(32);
    }
    __syncthreads();
    __threadfence();   // acquire pm

    {
        int sdir = cb / SCAN_PER_DIR;
        int bx   = cb - sdir * SCAN_PER_DIR;
        int nA   = sdir ? M : N;
        int nch  = sdir ? nch1 : nch0;
        const float2* A = sdir ? T : P;

        int p = bx * 256 + t;
        float v = 0.f;
        if (p < nA) {
            const float* src = pm + (size_t)sdir * chm * npm + p;
            float m = __uint_as_float(INFBITS);
#pragma unroll 16
            for (int c = 0; c < nch; ++c) m = fminf(m, src[(size_t)c * npm]);
            float2 a = A[p];
            v = m + fmaf(a.x, a.x, a.y * a.y);   // deferred ||a||^2
        }
        float s = block_sum256(v);
        __shared__ int is_last;
        if (t == 0) {
            bsum[cb] = s;
            __threadfence();
            unsigned int old = atomicAdd(cnt_scan, 1u);
            is_last = (old == (unsigned)(SCAN_BLOCKS - 1));
        }
        __syncthreads();
        if (!is_last) return;
    }

    // ---- combiner (last scanner) ----
    if (t == 0) {
        while (atomicAdd(cnt_dice, 0u) < (unsigned)DICE_BLOCKS)
            __builtin_amdgcn_s_sleep(32);
    }
    __syncthreads();
    __threadfence();

    float inter = 0.f, uni = 0.f, c0 = 0.f, c1 = 0.f;
    const volatile float* vi = inter_p;
    const volatile float* vu = uni_p;
    for (int i = t; i < DICE_BLOCKS; i += 256) { inter += vi[i]; uni += vu[i]; }
    const volatile float* vb = bsum;
    if (t < SCAN_PER_DIR)          c0 = vb[t];
    else if (t < SCAN_BLOCKS)      c1 = vb[t];

    float bi  = block_sum256(inter);
    float bu  = block_sum256(uni);
    float bc0 = block_sum256(c0);
    float bc1 = block_sum256(c1);
    if (t == 0) {
        const float SMOOTH = 1e-6f;
        float dice    = (2.f * bi + SMOOTH) / (bu + SMOOTH);
        float chamfer = bc0 / (float)N + bc1 / (float)M;
        out[0] = 0.5f * (1.f - dice) + 0.5f * chamfer;
    }
}

extern "C" void kernel_launch(void* const* d_in, const int* in_sizes, int n_in,
                              void* d_out, int out_size, void* d_ws, size_t ws_size,
                              hipStream_t stream) {
    const float*  pred = (const float*)d_in[0];
    const float*  targ = (const float*)d_in[1];
    const float2* pp   = (const float2*)d_in[2];
    const float2* tp   = (const float2*)d_in[3];
    int n = in_sizes[0];
    int N = in_sizes[2] / 2;
    int M = in_sizes[3] / 2;
    float* out = (float*)d_out;

    int npm  = N > M ? N : M;
    int nch0 = (M + TCH - 1) / TCH;
    int nch1 = (N + TCH - 1) / TCH;
    int chm  = nch0 > nch1 ? nch0 : nch1;
    int gxp  = (npm + PTS * 256 - 1) / (PTS * 256);
    int cham_blocks = 2 * gxp * chm;

    // ws layout: pm | inter_p[512] | uni_p[512] | bsum[64] | counters[3]
    char*  ws      = (char*)d_ws;
    float* pm      = (float*)ws;
    size_t pm_bytes = (size_t)2 * chm * npm * sizeof(float);
    size_t off     = (pm_bytes + 255) & ~(size_t)255;
    float* inter_p = (float*)(ws + off);
    float* uni_p   = inter_p + DICE_BLOCKS;
    float* bsum    = uni_p + DICE_BLOCKS;
    unsigned int* counters = (unsigned int*)(bsum + SCAN_BLOCKS);
    // counters[0]=cnt_dice, [1]=cnt_cham, [2]=cnt_scan

    hipMemsetAsync(counters, 0, 3 * sizeof(unsigned int), stream);

    int nblk = DICE_BLOCKS + cham_blocks;   // 512 + 512 = 1024 = 4 blocks/CU
    fused_one<<<nblk, 256, 0, stream>>>(
        (const float4*)pred, (const float4*)targ, n / 4,
        inter_p, uni_p, pp, tp, N, M, pm, npm, chm, gxp,
        cham_blocks, nch0, nch1, bsum,
        counters + 0, counters + 1, counters + 2, out);
}

// Round 15
// 29.233 us; speedup vs baseline: 3.8021x; 3.8021x over previous
//
#include <hip/hip_runtime.h>
#include <math.h>

#define INFBITS 0x7F800000u
#define TCH 256          // R15 lever: 128 -> 256 (halves pm traffic + K2 depth)
#define PTS 8            // query points per thread
#define DICE_BLOCKS 512

typedef float v2f __attribute__((ext_vector_type(2)));

// ---------- block-wide sum (blockDim.x == 256, 4 waves) ----------
__device__ __forceinline__ float block_sum256(float v) {
#pragma unroll
    for (int o = 32; o > 0; o >>= 1) v += __shfl_down(v, o, 64);
    __shared__ float sb[4];
    if ((threadIdx.x & 63) == 0) sb[threadIdx.x >> 6] = v;
    __syncthreads();
    float r = sb[0] + sb[1] + sb[2] + sb[3];
    __syncthreads();
    return r;
}

// ---------- K1: fused dice partials + chamfer partial mins ----------
// Structure = R13 (best, 27.9us; 2-kernel — R11/R12/R14 proved the kernel
// boundary is the cheapest global barrier on this chip). R15 lever: TCH=256.
// pm halves to 2 MB, K2 chunk depth halves to 32, per-block stage/prologue
// amortization doubles. Packed v_pk_fma_f32 inner loop from R13 unchanged.
__global__ void __launch_bounds__(256) fused_partials(
        const float4* __restrict__ p4, const float4* __restrict__ t4, int n4,
        float* __restrict__ inter_p, float* __restrict__ uni_p,
        const float2* __restrict__ P, const float2* __restrict__ T,
        int N, int M, float* __restrict__ pm, int npm, int chm, int gxp,
        unsigned int* __restrict__ counter) {
    int bid = blockIdx.x;
    if (bid == 0 && threadIdx.x == 0) *counter = 0u;   // reset K2's semaphore

    if (bid < DICE_BLOCKS) {
        float inter = 0.f, uni = 0.f;
#pragma unroll 2
        for (int i = bid * 256 + threadIdx.x; i < n4; i += DICE_BLOCKS * 256) {
            float4 p = p4[i];
            float4 t = t4[i];
            float s;
            s = __fdividef(1.f, 1.f + __expf(-p.x)); inter = fmaf(s, t.x, inter); uni += s + t.x;
            s = __fdividef(1.f, 1.f + __expf(-p.y)); inter = fmaf(s, t.y, inter); uni += s + t.y;
            s = __fdividef(1.f, 1.f + __expf(-p.z)); inter = fmaf(s, t.z, inter); uni += s + t.z;
            s = __fdividef(1.f, 1.f + __expf(-p.w)); inter = fmaf(s, t.w, inter); uni += s + t.w;
        }
        float bi = block_sum256(inter);
        float bu = block_sum256(uni);
        if (threadIdx.x == 0) { inter_p[bid] = bi; uni_p[bid] = bu; }
        return;
    }

    // ---- chamfer partials ----
    int cb      = bid - DICE_BLOCKS;
    int per_dir = gxp * chm;
    int dir     = cb / per_dir;
    int rem     = cb - dir * per_dir;
    int cy      = rem / gxp;          // target chunk
    int cx      = rem - cy * gxp;     // query-point group
    const float2* A = dir ? T : P;
    const float2* B = dir ? P : T;
    int nA = dir ? M : N;
    int nB = dir ? N : M;

    int tb = cy * TCH;
    if (tb >= nB) return;             // uniform per block

    // LDS: one float4 per j-PAIR, swizzled {b0x, b1x, b0y, b1y}
    __shared__ __align__(16) float4 qs[TCH / 2];
    int t = threadIdx.x;
    if (t < TCH / 2) {
        int j0 = tb + 2 * t;
        float4 r = make_float4(1e18f, 1e18f, 1e18f, 1e18f);  // pad never wins
        if (j0 + 1 < nB) {
            float4 b = *(const float4*)&B[j0];               // {b0x,b0y,b1x,b1y}
            r = make_float4(b.x, b.z, b.y, b.w);             // SoA pair swizzle
        } else if (j0 < nB) {
            float2 b = B[j0];
            r = make_float4(b.x, 1e18f, b.y, 1e18f);
        }
        qs[t] = r;
    }
    __syncthreads();

    int abase = cx * (PTS * 256);
    v2f nx2[PTS], ny2[PTS];
    float mn[PTS];
#pragma unroll
    for (int i = 0; i < PTS; ++i) {
        int p = abase + i * 256 + t;
        float nx = 0.f, ny = 0.f;
        mn[i] = __uint_as_float(INFBITS);
        if (p < nA) {
            float2 a = A[p];
            nx = -2.f * a.x;
            ny = -2.f * a.y;
        }
        nx2[i] = (v2f){nx, nx};
        ny2[i] = (v2f){ny, ny};
    }

    // packed inner loop: per j-pair S = X*X + Y*Y, per i 2 v_pk_fma + min fold
#pragma unroll 4
    for (int jp = 0; jp < TCH / 2; ++jp) {
        float4 q = qs[jp];                 // {b0x,b1x,b0y,b1y}
        v2f X = (v2f){q.x, q.y};
        v2f Y = (v2f){q.z, q.w};
        v2f S = X * X + Y * Y;
#pragma unroll
        for (int i = 0; i < PTS; ++i) {
            v2f D = nx2[i] * X + (ny2[i] * Y + S);
            mn[i] = fminf(fminf(mn[i], D.x), D.y);
        }
    }

    float* dstc = pm + ((size_t)dir * chm + cy) * npm;
#pragma unroll
    for (int i = 0; i < PTS; ++i) {
        int p = abase + i * 256 + t;
        if (p < nA) dstc[p] = mn[i];
    }
}

// ---------- K2: fused finalize ----------
// grid = 2*gxf blocks; per-point min across chunks, + ||a||^2, block sum;
// last block combines dice partials + chamfer block sums into the scalar.
__global__ void __launch_bounds__(256) finalize_all(
        const float* __restrict__ pm, int npm, int chm,
        int N, int M, int nch0, int nch1,
        const float2* __restrict__ P, const float2* __restrict__ T,
        const float* __restrict__ inter_p, const float* __restrict__ uni_p,
        float* __restrict__ bsum, unsigned int* __restrict__ counter,
        int gxf, float* __restrict__ out) {
    int blk = blockIdx.x;
    int dir = blk / gxf;
    int bx  = blk - dir * gxf;
    int nA  = dir ? M : N;
    int nch = dir ? nch1 : nch0;
    const float2* A = dir ? T : P;

    int p = bx * 256 + threadIdx.x;
    float v = 0.f;
    if (p < nA) {
        const float* src = pm + (size_t)dir * chm * npm + p;
        float m = __uint_as_float(INFBITS);
#pragma unroll 16
        for (int c = 0; c < nch; ++c) m = fminf(m, src[(size_t)c * npm]);
        float2 a = A[p];
        v = m + fmaf(a.x, a.x, a.y * a.y);   // add the deferred ||a||^2
    }
    float s = block_sum256(v);

    __shared__ int is_last;
    if (threadIdx.x == 0) {
        bsum[blk] = s;
        __threadfence();
        unsigned int old = atomicAdd(counter, 1u);
        is_last = (old == (unsigned)(2 * gxf - 1));
    }
    __syncthreads();
    if (!is_last) return;
    __threadfence();

    float inter = 0.f, uni = 0.f, c0 = 0.f, c1 = 0.f;
    for (int i = threadIdx.x; i < DICE_BLOCKS; i += 256) {
        inter += inter_p[i];
        uni   += uni_p[i];
    }
    const volatile float* vb = bsum;
    for (int i = threadIdx.x; i < gxf; i += 256) {
        c0 += vb[i];
        c1 += vb[gxf + i];
    }
    float bi  = block_sum256(inter);
    float bu  = block_sum256(uni);
    float bc0 = block_sum256(c0);
    float bc1 = block_sum256(c1);
    if (threadIdx.x == 0) {
        const float SMOOTH = 1e-6f;
        float dice    = (2.f * bi + SMOOTH) / (bu + SMOOTH);
        float chamfer = bc0 / (float)N + bc1 / (float)M;
        out[0] = 0.5f * (1.f - dice) + 0.5f * chamfer;
    }
}

extern "C" void kernel_launch(void* const* d_in, const int* in_sizes, int n_in,
                              void* d_out, int out_size, void* d_ws, size_t ws_size,
                              hipStream_t stream) {
    const float*  pred = (const float*)d_in[0];
    const float*  targ = (const float*)d_in[1];
    const float2* pp   = (const float2*)d_in[2];
    const float2* tp   = (const float2*)d_in[3];
    int n = in_sizes[0];
    int N = in_sizes[2] / 2;
    int M = in_sizes[3] / 2;
    float* out = (float*)d_out;

    int npm  = N > M ? N : M;
    int nch0 = (M + TCH - 1) / TCH;
    int nch1 = (N + TCH - 1) / TCH;
    int chm  = nch0 > nch1 ? nch0 : nch1;
    int gxp  = (npm + PTS * 256 - 1) / (PTS * 256);
    int gxf  = (npm + 255) / 256;

    // ws layout: pm | inter_p | uni_p | bsum | counter
    char*  ws      = (char*)d_ws;
    float* pm      = (float*)ws;
    size_t pm_bytes = (size_t)2 * chm * npm * sizeof(float);
    size_t off     = (pm_bytes + 255) & ~(size_t)255;
    float* inter_p = (float*)(ws + off);
    float* uni_p   = inter_p + DICE_BLOCKS;
    float* bsum    = uni_p + DICE_BLOCKS;
    unsigned int* counter = (unsigned int*)(bsum + 2 * gxf);

    int cham_blocks = 2 * gxp * chm;
    fused_partials<<<DICE_BLOCKS + cham_blocks, 256, 0, stream>>>(
        (const float4*)pred, (const float4*)targ, n / 4,
        inter_p, uni_p, pp, tp, N, M, pm, npm, chm, gxp, counter);

    finalize_all<<<2 * gxf, 256, 0, stream>>>(pm, npm, chm, N, M, nch0, nch1,
                                              pp, tp, inter_p, uni_p, bsum,
                                              counter, gxf, out);
}

// Round 16
// 28.896 us; speedup vs baseline: 3.8465x; 1.0117x over previous
//
#include <hip/hip_runtime.h>
#include <math.h>

#define INFBITS 0x7F800000u
#define TCH 128          // measured optimum: 32:36.5 / 64:30.1 / 128:27.9 / 256:29.2
#define PTS 8            // measured optimum (16 -> VGPR cliff, R8)
#define DICE_BLOCKS 512

typedef float v2f __attribute__((ext_vector_type(2)));

// ---------- block-wide sum (blockDim.x == 256, 4 waves) ----------
__device__ __forceinline__ float block_sum256(float v) {
#pragma unroll
    for (int o = 32; o > 0; o >>= 1) v += __shfl_down(v, o, 64);
    __shared__ float sb[4];
    if ((threadIdx.x & 63) == 0) sb[threadIdx.x >> 6] = v;
    __syncthreads();
    float r = sb[0] + sb[1] + sb[2] + sb[3];
    __syncthreads();
    return r;
}

// ---------- K1: fused dice partials + chamfer partial mins ----------
// FINAL structure (R13, best measured 27.9us):
//  - 2 kernels; kernel boundary is the cheapest global barrier on this chip
//    (persistent/atomicMin/segregated variants: 110/79/45us — all refuted).
//  - dice (HBM-bound) and chamfer (VALU-bound) co-resident in K1: overlap
//    confirmed (segregating them cost +16us, R12).
//  - chamfer inner loop: packed v2f -> v_pk_fma_f32 + v_min3_f32; LDS holds
//    j-pairs pre-swizzled {b0x,b1x,b0y,b1y}; ||b||^2 recomputed in VALU;
//    ||a||^2 deferred to K2 (min invariant to per-point constant).
//  - VGPR kept < 64 for 8 waves/SIMD (R4 spill / R5+R8 occupancy lessons).
__global__ void __launch_bounds__(256) fused_partials(
        const float4* __restrict__ p4, const float4* __restrict__ t4, int n4,
        float* __restrict__ inter_p, float* __restrict__ uni_p,
        const float2* __restrict__ P, const float2* __restrict__ T,
        int N, int M, float* __restrict__ pm, int npm, int chm, int gxp,
        unsigned int* __restrict__ counter) {
    int bid = blockIdx.x;
    if (bid == 0 && threadIdx.x == 0) *counter = 0u;   // reset K2's semaphore

    if (bid < DICE_BLOCKS) {
        float inter = 0.f, uni = 0.f;
#pragma unroll 2
        for (int i = bid * 256 + threadIdx.x; i < n4; i += DICE_BLOCKS * 256) {
            float4 p = p4[i];
            float4 t = t4[i];
            float s;
            s = __fdividef(1.f, 1.f + __expf(-p.x)); inter = fmaf(s, t.x, inter); uni += s + t.x;
            s = __fdividef(1.f, 1.f + __expf(-p.y)); inter = fmaf(s, t.y, inter); uni += s + t.y;
            s = __fdividef(1.f, 1.f + __expf(-p.z)); inter = fmaf(s, t.z, inter); uni += s + t.z;
            s = __fdividef(1.f, 1.f + __expf(-p.w)); inter = fmaf(s, t.w, inter); uni += s + t.w;
        }
        float bi = block_sum256(inter);
        float bu = block_sum256(uni);
        if (threadIdx.x == 0) { inter_p[bid] = bi; uni_p[bid] = bu; }
        return;
    }

    // ---- chamfer partials ----
    int cb      = bid - DICE_BLOCKS;
    int per_dir = gxp * chm;
    int dir     = cb / per_dir;
    int rem     = cb - dir * per_dir;
    int cy      = rem / gxp;          // target chunk
    int cx      = rem - cy * gxp;     // query-point group
    const float2* A = dir ? T : P;
    const float2* B = dir ? P : T;
    int nA = dir ? M : N;
    int nB = dir ? N : M;

    int tb = cy * TCH;
    if (tb >= nB) return;             // uniform per block

    // LDS: one float4 per j-PAIR, swizzled {b0x, b1x, b0y, b1y}
    __shared__ __align__(16) float4 qs[TCH / 2];
    int t = threadIdx.x;
    if (t < TCH / 2) {
        int j0 = tb + 2 * t;
        float4 r = make_float4(1e18f, 1e18f, 1e18f, 1e18f);  // pad never wins
        if (j0 + 1 < nB) {
            float4 b = *(const float4*)&B[j0];               // {b0x,b0y,b1x,b1y}
            r = make_float4(b.x, b.z, b.y, b.w);             // SoA pair swizzle
        } else if (j0 < nB) {
            float2 b = B[j0];
            r = make_float4(b.x, 1e18f, b.y, 1e18f);
        }
        qs[t] = r;
    }
    __syncthreads();

    int abase = cx * (PTS * 256);
    v2f nx2[PTS], ny2[PTS];
    float mn[PTS];
#pragma unroll
    for (int i = 0; i < PTS; ++i) {
        int p = abase + i * 256 + t;
        float nx = 0.f, ny = 0.f;
        mn[i] = __uint_as_float(INFBITS);
        if (p < nA) {
            float2 a = A[p];
            nx = -2.f * a.x;
            ny = -2.f * a.y;
        }
        nx2[i] = (v2f){nx, nx};
        ny2[i] = (v2f){ny, ny};
    }

    // packed inner loop: per j-pair S = X*X + Y*Y, per i 2 v_pk_fma + min fold
#pragma unroll 4
    for (int jp = 0; jp < TCH / 2; ++jp) {
        float4 q = qs[jp];                 // {b0x,b1x,b0y,b1y}
        v2f X = (v2f){q.x, q.y};
        v2f Y = (v2f){q.z, q.w};
        v2f S = X * X + Y * Y;
#pragma unroll
        for (int i = 0; i < PTS; ++i) {
            v2f D = nx2[i] * X + (ny2[i] * Y + S);
            mn[i] = fminf(fminf(mn[i], D.x), D.y);
        }
    }

    float* dstc = pm + ((size_t)dir * chm + cy) * npm;
#pragma unroll
    for (int i = 0; i < PTS; ++i) {
        int p = abase + i * 256 + t;
        if (p < nA) dstc[p] = mn[i];
    }
}

// ---------- K2: fused finalize ----------
// grid = 2*gxf blocks; per-point min across chunks, + ||a||^2, block sum;
// last block combines dice partials + chamfer block sums into the scalar.
__global__ void __launch_bounds__(256) finalize_all(
        const float* __restrict__ pm, int npm, int chm,
        int N, int M, int nch0, int nch1,
        const float2* __restrict__ P, const float2* __restrict__ T,
        const float* __restrict__ inter_p, const float* __restrict__ uni_p,
        float* __restrict__ bsum, unsigned int* __restrict__ counter,
        int gxf, float* __restrict__ out) {
    int blk = blockIdx.x;
    int dir = blk / gxf;
    int bx  = blk - dir * gxf;
    int nA  = dir ? M : N;
    int nch = dir ? nch1 : nch0;
    const float2* A = dir ? T : P;

    int p = bx * 256 + threadIdx.x;
    float v = 0.f;
    if (p < nA) {
        const float* src = pm + (size_t)dir * chm * npm + p;
        float m = __uint_as_float(INFBITS);
#pragma unroll 16
        for (int c = 0; c < nch; ++c) m = fminf(m, src[(size_t)c * npm]);
        float2 a = A[p];
        v = m + fmaf(a.x, a.x, a.y * a.y);   // add the deferred ||a||^2
    }
    float s = block_sum256(v);

    __shared__ int is_last;
    if (threadIdx.x == 0) {
        bsum[blk] = s;
        __threadfence();
        unsigned int old = atomicAdd(counter, 1u);
        is_last = (old == (unsigned)(2 * gxf - 1));
    }
    __syncthreads();
    if (!is_last) return;
    __threadfence();

    float inter = 0.f, uni = 0.f, c0 = 0.f, c1 = 0.f;
    for (int i = threadIdx.x; i < DICE_BLOCKS; i += 256) {
        inter += inter_p[i];
        uni   += uni_p[i];
    }
    const volatile float* vb = bsum;
    for (int i = threadIdx.x; i < gxf; i += 256) {
        c0 += vb[i];
        c1 += vb[gxf + i];
    }
    float bi  = block_sum256(inter);
    float bu  = block_sum256(uni);
    float bc0 = block_sum256(c0);
    float bc1 = block_sum256(c1);
    if (threadIdx.x == 0) {
        const float SMOOTH = 1e-6f;
        float dice    = (2.f * bi + SMOOTH) / (bu + SMOOTH);
        float chamfer = bc0 / (float)N + bc1 / (float)M;
        out[0] = 0.5f * (1.f - dice) + 0.5f * chamfer;
    }
}

extern "C" void kernel_launch(void* const* d_in, const int* in_sizes, int n_in,
                              void* d_out, int out_size, void* d_ws, size_t ws_size,
                              hipStream_t stream) {
    const float*  pred = (const float*)d_in[0];
    const float*  targ = (const float*)d_in[1];
    const float2* pp   = (const float2*)d_in[2];
    const float2* tp   = (const float2*)d_in[3];
    int n = in_sizes[0];
    int N = in_sizes[2] / 2;
    int M = in_sizes[3] / 2;
    float* out = (float*)d_out;

    int npm  = N > M ? N : M;
    int nch0 = (M + TCH - 1) / TCH;
    int nch1 = (N + TCH - 1) / TCH;
    int chm  = nch0 > nch1 ? nch0 : nch1;
    int gxp  = (npm + PTS * 256 - 1) / (PTS * 256);
    int gxf  = (npm + 255) / 256;

    // ws layout: pm | inter_p | uni_p | bsum | counter
    char*  ws      = (char*)d_ws;
    float* pm      = (float*)ws;
    size_t pm_bytes = (size_t)2 * chm * npm * sizeof(float);
    size_t off     = (pm_bytes + 255) & ~(size_t)255;
    float* inter_p = (float*)(ws + off);
    float* uni_p   = inter_p + DICE_BLOCKS;
    float* bsum    = uni_p + DICE_BLOCKS;
    unsigned int* counter = (unsigned int*)(bsum + 2 * gxf);

    int cham_blocks = 2 * gxp * chm;
    fused_partials<<<DICE_BLOCKS + cham_blocks, 256, 0, stream>>>(
        (const float4*)pred, (const float4*)targ, n / 4,
        inter_p, uni_p, pp, tp, N, M, pm, npm, chm, gxp, counter);

    finalize_all<<<2 * gxf, 256, 0, stream>>>(pm, npm, chm, N, M, nch0, nch1,
                                              pp, tp, inter_p, uni_p, bsum,
                                              counter, gxf, out);
}